// Round 14
// baseline (193.620 us; speedup 1.0000x reference)
//
#include <hip/hip_runtime.h>
#include <hip/hip_bf16.h>

#define B_  16
#define N_  128
#define NF_ 128
#define H_  128

typedef __attribute__((ext_vector_type(8))) short short8;
typedef __attribute__((ext_vector_type(4))) short short4v;
typedef __attribute__((ext_vector_type(4))) float floatx4;

__device__ __forceinline__ float silu_f(float x) {
    return x * __builtin_amdgcn_rcpf(1.0f + __expf(-x));
}
__device__ __forceinline__ float sigm_f(float x) {
    return __builtin_amdgcn_rcpf(1.0f + __expf(-x));
}
__device__ __forceinline__ unsigned short f2bf(float x) {   // RNE
    union { float f; unsigned u; } v; v.f = x;
    unsigned r = (v.u + 0x7FFFu + ((v.u >> 16) & 1u)) >> 16;
    return (unsigned short)r;
}
__device__ __forceinline__ short f2bf_fast(float x) {       // native cvt
    union { __hip_bfloat16 h; short s; } u;
    u.h = __float2bfloat16(x);
    return u.s;
}
__device__ __forceinline__ float bf2f(unsigned short s) {
    union { unsigned u; float f; } v; v.u = ((unsigned)s) << 16;
    return v.f;
}
// byte offset of bf16 element k in a 256B row with 16-slot XOR swizzle
__device__ __forceinline__ int swz(int row, int k) {
    return row * 256 + ((((k >> 3) ^ (row & 15)) << 4) | ((k & 7) << 1));
}

// K=16 bf16 MFMA (A,B = 4 bf16 each)
#if defined(__has_builtin) && __has_builtin(__builtin_amdgcn_mfma_f32_16x16x16bf16_1k)
#define MFMA16(a, b, c) __builtin_amdgcn_mfma_f32_16x16x16bf16_1k(a, b, c, 0, 0, 0)
#else
__device__ __forceinline__ floatx4 mfma16_asm(short4v a, short4v b, floatx4 c) {
    floatx4 d;
    asm volatile("v_mfma_f32_16x16x16_bf16 %0, %1, %2, %3"
                 : "=v"(d) : "v"(a), "v"(b), "v"(c));
    return d;
}
#define MFMA16(a, b, c) mfma16_asm(a, b, c)
#endif

// ---------------- k1: per-node precompute A = nf@We1[0:128], Bm = nf@We1[128:256]
__global__ __launch_bounds__(128) void k1_pre(const float* __restrict__ nf,
                                              const float* __restrict__ We1,
                                              float* __restrict__ A_ws,
                                              float* __restrict__ Bm_ws) {
    const int b  = blockIdx.x >> 4;
    const int r0 = (blockIdx.x & 15) << 3;
    const int h  = threadIdx.x;
    __shared__ float rows[8][128];
#pragma unroll
    for (int r = 0; r < 8; ++r)
        rows[r][h] = nf[((size_t)(b * N_ + r0 + r)) * NF_ + h];
    __syncthreads();
    float a[8], bm[8];
#pragma unroll
    for (int r = 0; r < 8; ++r) { a[r] = 0.f; bm[r] = 0.f; }
    for (int c = 0; c < NF_; ++c) {
        const float w1 = We1[c * H_ + h];
        const float w2 = We1[(NF_ + c) * H_ + h];
#pragma unroll
        for (int r = 0; r < 8; ++r) {
            const float x = rows[r][c];
            a[r]  = fmaf(x, w1, a[r]);
            bm[r] = fmaf(x, w2, bm[r]);
        }
    }
#pragma unroll
    for (int r = 0; r < 8; ++r) {
        A_ws [((size_t)(b * N_ + r0 + r)) * H_ + h] = a[r];
        Bm_ws[((size_t)(b * N_ + r0 + r)) * H_ + h] = bm[r];
    }
}

// ---------------- kC: Cinv[b] = 1/(sum_j valid - 1)
__global__ __launch_bounds__(64) void kC(const float* __restrict__ valid,
                                         float* __restrict__ Cinv) {
    const int b = blockIdx.x;
    const int t = threadIdx.x;
    float v = valid[b * N_ + t] + valid[b * N_ + 64 + t];
#pragma unroll
    for (int m = 32; m >= 1; m >>= 1) v += __shfl_down(v, m, 64);
    if (t == 0) Cinv[b] = 1.0f / (v - 1.0f);
}

// ---------------- k2: swapped-MFMA edge pipeline (edge = lr lane-local) --------
// LDS layout (bytes); total 110272 < 160 KiB
#define OFF_BM    0         // 32768: Bm bf16 [128] rows x 256 B, swizzled
#define OFF_W2T   32768     // 32768: We2^T bf16, swizzled
#define OFF_WC1X  65536     // 36864: [Wc1^T | Wi | 0] bf16 144 rows, swizzled
#define OFF_AW    102400    // 4096: 8 A-rows f32
#define OFF_WAB   106496    // 1024: We1 rows 256/257 f32
#define OFF_WC2   107520    // 512
#define OFF_POSJ  108032    // 1536
#define OFF_VALJ  109568    // 512
#define OFF_POSI  110080    // 96 (pad 128)
#define OFF_VALI  110208    // 32 (pad 64)
#define SMEM_K2   110272

__global__ __launch_bounds__(512, 2) void k2_edge(
        const float* __restrict__ pos,
        const float* __restrict__ valid,
        const float* __restrict__ adj,
        const float* __restrict__ We1,
        const float* __restrict__ We2,
        const float* __restrict__ Wc1,
        const float* __restrict__ Wc2,
        const float* __restrict__ Wi,
        const float* __restrict__ A_ws,
        const float* __restrict__ Bm_ws,
        const float* __restrict__ Cinv,
        float* __restrict__ msg_ws,
        float* __restrict__ pos_out) {
    __shared__ __align__(16) char smem[SMEM_K2];
    char* BMb   = smem + OFF_BM;
    char* W2Tb  = smem + OFF_W2T;
    char* WC1Xb = smem + OFF_WC1X;
    float* AWf  = (float*)(smem + OFF_AW);
    float* WABf = (float*)(smem + OFF_WAB);
    float* wc2s = (float*)(smem + OFF_WC2);
    float* posj = (float*)(smem + OFF_POSJ);
    float* valj = (float*)(smem + OFF_VALJ);
    float* posi = (float*)(smem + OFF_POSI);
    float* vali = (float*)(smem + OFF_VALI);

    const int tid = threadIdx.x;
    const int b   = blockIdx.x >> 4;
    const int i0  = (blockIdx.x & 15) << 3;

    // ---- staging ----
    for (int q = tid; q < (N_ * H_) / 4; q += 512) {       // Bm -> bf16, swizzled
        const int j  = q >> 5;
        const int ch = (q << 2) & 127;
        const float4 v = *(const float4*)(Bm_ws + ((size_t)(b * N_ + j)) * H_ + ch);
        ushort4 o;
        o.x = f2bf(v.x); o.y = f2bf(v.y); o.z = f2bf(v.z); o.w = f2bf(v.w);
        *(ushort4*)(BMb + swz(j, ch)) = o;
    }
    for (int x = tid; x < H_ * H_; x += 512) {             // We2^T, swizzled
        const int k = x >> 7, n = x & 127;
        *(unsigned short*)(W2Tb + swz(n, k)) = f2bf(We2[x]);
    }
    for (int x = tid; x < H_ * H_; x += 512) {             // Wc1^T, swizzled
        const int k = x >> 7, n = x & 127;
        *(unsigned short*)(WC1Xb + swz(n, k)) = f2bf(Wc1[x]);
    }
    if (tid < 128)                                          // Wi -> row 128 (key 0)
        *(unsigned short*)(WC1Xb + swz(128, tid)) = f2bf(Wi[tid]);
    for (int x = tid; x < 15 * 128; x += 512)               // zero rows 129..143
        ((unsigned short*)(WC1Xb + 129 * 256))[x] = 0;
    for (int x = tid; x < 8 * H_; x += 512)                 // A rows f32
        AWf[x] = A_ws[((size_t)(b * N_ + i0)) * H_ + x];
    if (tid < 256) WABf[tid] = We1[256 * H_ + tid];         // rows 256/257 f32
    if (tid < 128) {
        wc2s[tid] = Wc2[tid];
        valj[tid] = valid[b * N_ + tid];
    }
    if (tid >= 128) posj[tid - 128] = pos[b * N_ * 3 + (tid - 128)];   // 384 floats
    if (tid < 24)   posi[tid] = pos[b * N_ * 3 + i0 * 3 + tid];
    if (tid >= 32 && tid < 40) vali[tid - 32] = valid[b * N_ + i0 + (tid - 32)];
    __syncthreads();

    const int w  = tid >> 6;
    const int l  = tid & 63;
    const int lr = l & 15;
    const int lg = l >> 4;
    const int i  = i0 + w;

    int csx[4];                                  // K=32 fragment slot offsets
#pragma unroll
    for (int ks = 0; ks < 4; ++ks) csx[ks] = ((ks * 4 + lg) ^ lr) << 4;
    int cs16[8];                                 // K=16 fragment byte offsets
#pragma unroll
    for (int ks = 0; ks < 8; ++ks)
        cs16[ks] = ((((2 * ks + (lg >> 1)) ^ lr) << 4) | ((lg & 1) << 3));

    const float vi   = vali[w];
    const float pix  = posi[w * 3 + 0], piy = posi[w * 3 + 1], piz = posi[w * 3 + 2];
    const float cinv = Cinv[b];

    floatx4 msgv[8];
    const floatx4 zf = {0.f, 0.f, 0.f, 0.f};
#pragma unroll
    for (int nt = 0; nt < 8; ++nt) msgv[nt] = zf;
    float px = 0.f, py = 0.f, pz = 0.f;

    for (int jp = 0; jp < 4; ++jp) {            // 2 chunks of 16 edges per pass
        const int j0 = jp * 32;
        float adjv[2], vmv[2], dst[2], vnx[2], vny[2], vnz[2];
#pragma unroll
        for (int c = 0; c < 2; ++c) {
            const int jj = j0 + c * 16 + lr;    // edge owned by THIS lane
            adjv[c] = adj[((size_t)(b * N_ + i)) * N_ + jj];
            const float vj = valj[jj];
            const float vx = pix - posj[jj * 3 + 0];
            const float vy = piy - posj[jj * 3 + 1];
            const float vz = piz - posj[jj * 3 + 2];
            dst[c] = vx * vx + vy * vy + vz * vz;
            vmv[c] = vi * vj;
            const float rn = __builtin_amdgcn_rcpf(fmaxf(sqrtf(dst[c]), 1e-10f));
            vnx[c] = vx * rn; vny[c] = vy * rn; vnz[c] = vz * rn;
        }

        // ---- preact build + silu -> B-fragments (edge = lr), both chunks ----
        short8 af[2][4];
#pragma unroll
        for (int c = 0; c < 2; ++c) {
            const int jj = j0 + c * 16 + lr;
#pragma unroll
            for (int ks = 0; ks < 4; ++ks) {
                const int co = ks * 32 + lg * 8;
                const short8 bm8 = *(const short8*)(BMb + jj * 256 + csx[ks]);
                const floatx4 a0 = *(const floatx4*)(AWf + w * 128 + co);
                const floatx4 a1 = *(const floatx4*)(AWf + w * 128 + co + 4);
                const floatx4 wa0 = *(const floatx4*)(WABf + co);
                const floatx4 wa1 = *(const floatx4*)(WABf + co + 4);
                const floatx4 wb0 = *(const floatx4*)(WABf + 128 + co);
                const floatx4 wb1 = *(const floatx4*)(WABf + 128 + co + 4);
#pragma unroll
                for (int e = 0; e < 8; ++e) {
                    const float aw = (e < 4) ? a0[e & 3] : a1[e & 3];
                    const float wa = (e < 4) ? wa0[e & 3] : wa1[e & 3];
                    const float wb = (e < 4) ? wb0[e & 3] : wb1[e & 3];
                    const float pre = aw + bf2f((unsigned short)bm8[e])
                                    + dst[c] * wa + adjv[c] * wb;
                    af[c][ks][e] = f2bf_fast(silu_f(pre));
                }
            }
        }

        // ---- GEMM1 (swapped): z1^T tile = mfma(A=We2^T, B=pre^T) ----
        // D: lane holds edge lr, channel nt*16 + 4*lg + r
        floatx4 acc1[2][8];
#pragma unroll
        for (int c = 0; c < 2; ++c)
#pragma unroll
            for (int nt = 0; nt < 8; ++nt) acc1[c][nt] = zf;
#pragma unroll
        for (int nt = 0; nt < 8; ++nt)
#pragma unroll
            for (int ks = 0; ks < 4; ++ks) {
                const short8 bf = *(const short8*)(W2Tb + (nt * 16 + lr) * 256 + csx[ks]);
                acc1[0][nt] = __builtin_amdgcn_mfma_f32_16x16x32_bf16(bf, af[0][ks], acc1[0][nt], 0, 0, 0);
                acc1[1][nt] = __builtin_amdgcn_mfma_f32_16x16x32_bf16(bf, af[1][ks], acc1[1][nt], 0, 0, 0);
            }
        // m = silu(.)
#pragma unroll
        for (int c = 0; c < 2; ++c)
#pragma unroll
            for (int nt = 0; nt < 8; ++nt)
#pragma unroll
                for (int r = 0; r < 4; ++r)
                    acc1[c][nt][r] = silu_f(acc1[c][nt][r]);

        // ---- af2: K=16 B-fragment = lane-local pack of m (no exchange!) ----
        short4v af2[2][8];
#pragma unroll
        for (int c = 0; c < 2; ++c)
#pragma unroll
            for (int ks = 0; ks < 8; ++ks) {
                short4v t;
                t[0] = f2bf_fast(acc1[c][ks][0]);
                t[1] = f2bf_fast(acc1[c][ks][1]);
                t[2] = f2bf_fast(acc1[c][ks][2]);
                t[3] = f2bf_fast(acc1[c][ks][3]);
                af2[c][ks] = t;
            }

        // ---- gate: e-preact tile (Wi row 128), K=16 ----
        floatx4 accg[2];
        accg[0] = zf; accg[1] = zf;
#pragma unroll
        for (int ks = 0; ks < 8; ++ks) {
            const short4v ga = *(const short4v*)(WC1Xb + (128 + lr) * 256 + cs16[ks]);
            accg[0] = MFMA16(ga, af2[0][ks], accg[0]);
            accg[1] = MFMA16(ga, af2[1][ks], accg[1]);
        }
#pragma unroll
        for (int c = 0; c < 2; ++c) {
            const float ep = __shfl(accg[c][0], lr);   // lane lr (lg=0) holds chan 0
            const float t  = sigm_f(ep) * adjv[c];     // all lane-local
#pragma unroll
            for (int nt = 0; nt < 8; ++nt)
                msgv[nt] += acc1[c][nt] * t;
        }

        // ---- GEMM2 (swapped, K=16): y2^T tiles streamed; phi scalar ----
        float ph[2] = {0.f, 0.f};
#pragma unroll
        for (int nt = 0; nt < 8; ++nt) {
            floatx4 acc2a = zf, acc2b = zf;
#pragma unroll
            for (int ks = 0; ks < 8; ++ks) {
                const short4v wf = *(const short4v*)(WC1Xb + (nt * 16 + lr) * 256 + cs16[ks]);
                acc2a = MFMA16(wf, af2[0][ks], acc2a);
                acc2b = MFMA16(wf, af2[1][ks], acc2b);
            }
            const floatx4 wv4 = *(const floatx4*)(wc2s + nt * 16 + 4 * lg);
#pragma unroll
            for (int r = 0; r < 4; ++r) {
                ph[0] = fmaf(silu_f(acc2a[r]), wv4[r], ph[0]);
                ph[1] = fmaf(silu_f(acc2b[r]), wv4[r], ph[1]);
            }
        }
#pragma unroll
        for (int c = 0; c < 2; ++c) {
            ph[c] += __shfl_xor(ph[c], 16);
            ph[c] += __shfl_xor(ph[c], 32);            // phi for edge lr, all lanes
            const float pm = ph[c] * vmv[c];
            px = fmaf(vnx[c], pm, px); py = fmaf(vny[c], pm, py); pz = fmaf(vnz[c], pm, pz);
        }
    }

    // ---- epilogue ----
#pragma unroll
    for (int msk = 1; msk <= 8; msk <<= 1)
#pragma unroll
        for (int nt = 0; nt < 8; ++nt)
#pragma unroll
            for (int r = 0; r < 4; ++r)
                msgv[nt][r] += __shfl_xor(msgv[nt][r], msk);
    if (lr == 0) {                                   // 4 lanes/wave (lg=0..3)
#pragma unroll
        for (int nt = 0; nt < 8; ++nt)
            *(floatx4*)(msg_ws + ((size_t)(b * N_ + i)) * H_ + nt * 16 + 4 * lg) = msgv[nt];
    }
    // pos: lanes within lg==const groups hold duplicates; masks 1..8 stay in-group
#pragma unroll
    for (int msk = 1; msk <= 8; msk <<= 1) {
        px += __shfl_xor(px, msk);
        py += __shfl_xor(py, msk);
        pz += __shfl_xor(pz, msk);
    }
    if (l == 0) {
        const size_t o = ((size_t)(b * N_ + i)) * 3;
        pos_out[o + 0] = pos[o + 0] + cinv * px;
        pos_out[o + 1] = pos[o + 1] + cinv * py;
        pos_out[o + 2] = pos[o + 2] + cinv * pz;
    }
}

// ---------------- k3: node MLP ----------------
__global__ __launch_bounds__(128) void k3_node(
        const float* __restrict__ nf,
        const float* __restrict__ Wn1,
        const float* __restrict__ Wn2,
        const float* __restrict__ msg_ws,
        float* __restrict__ out) {
    const int b  = blockIdx.x >> 4;
    const int r0 = (blockIdx.x & 15) << 3;
    const int h  = threadIdx.x;
    __shared__ float in_s[8][256];
    __shared__ float t_s[8][128];
#pragma unroll
    for (int r = 0; r < 8; ++r) {
        in_s[r][h]       = nf[((size_t)(b * N_ + r0 + r)) * NF_ + h];
        in_s[r][128 + h] = msg_ws[((size_t)(b * N_ + r0 + r)) * H_ + h];
    }
    __syncthreads();
    float acc[8];
#pragma unroll
    for (int r = 0; r < 8; ++r) acc[r] = 0.f;
    for (int c = 0; c < 256; ++c) {
        const float wv = Wn1[c * H_ + h];
#pragma unroll
        for (int r = 0; r < 8; ++r) acc[r] = fmaf(in_s[r][c], wv, acc[r]);
    }
#pragma unroll
    for (int r = 0; r < 8; ++r) t_s[r][h] = silu_f(acc[r]);
    __syncthreads();
    float o[8];
#pragma unroll
    for (int r = 0; r < 8; ++r) o[r] = 0.f;
    for (int c = 0; c < 128; ++c) {
        const float wv = Wn2[c * NF_ + h];
#pragma unroll
        for (int r = 0; r < 8; ++r) o[r] = fmaf(t_s[r][c], wv, o[r]);
    }
#pragma unroll
    for (int r = 0; r < 8; ++r)
        out[((size_t)(b * N_ + r0 + r)) * NF_ + h] = in_s[r][h] + o[r];
}

extern "C" void kernel_launch(void* const* d_in, const int* in_sizes, int n_in,
                              void* d_out, int out_size, void* d_ws, size_t ws_size,
                              hipStream_t stream) {
    const float* node_feat = (const float*)d_in[0];
    const float* pos   = (const float*)d_in[1];
    const float* valid = (const float*)d_in[2];
    const float* adj   = (const float*)d_in[3];
    const float* We1   = (const float*)d_in[4];
    const float* We2   = (const float*)d_in[5];
    const float* Wc1   = (const float*)d_in[6];
    const float* Wc2   = (const float*)d_in[7];
    const float* Wn1   = (const float*)d_in[8];
    const float* Wn2   = (const float*)d_in[9];
    const float* Wi    = (const float*)d_in[10];

    float* out     = (float*)d_out;
    float* pos_out = out + (size_t)B_ * N_ * NF_;

    const size_t node_elems = (size_t)B_ * N_ * H_;
    if (ws_size < (3 * node_elems + B_) * sizeof(float)) return;
    float* A_ws   = (float*)d_ws;
    float* Bm_ws  = A_ws + node_elems;
    float* msg_ws = Bm_ws + node_elems;
    float* Cinv   = msg_ws + node_elems;

    k1_pre<<<B_ * 16, 128, 0, stream>>>(node_feat, We1, A_ws, Bm_ws);
    kC<<<B_, 64, 0, stream>>>(valid, Cinv);
    k2_edge<<<B_ * 16, 512, 0, stream>>>(pos, valid, adj, We1, We2, Wc1, Wc2, Wi,
                                         A_ws, Bm_ws, Cinv, msg_ws, pos_out);
    k3_node<<<B_ * 16, 128, 0, stream>>>(node_feat, Wn1, Wn2, msg_ws, out);
}

// Round 15
// 73.091 us; speedup vs baseline: 2.6490x; 2.6490x over previous
//
#include <hip/hip_runtime.h>
#include <hip/hip_bf16.h>

#define B_  16
#define N_  128
#define NF_ 128
#define H_  128

typedef __attribute__((ext_vector_type(8))) short short8;
typedef __attribute__((ext_vector_type(4))) float floatx4;

__device__ __forceinline__ float silu_f(float x) {
    return x * __builtin_amdgcn_rcpf(1.0f + __expf(-x));
}
__device__ __forceinline__ float sigm_f(float x) {
    return __builtin_amdgcn_rcpf(1.0f + __expf(-x));
}
__device__ __forceinline__ unsigned short f2bf(float x) {   // RNE
    union { float f; unsigned u; } v; v.f = x;
    unsigned r = (v.u + 0x7FFFu + ((v.u >> 16) & 1u)) >> 16;
    return (unsigned short)r;
}
__device__ __forceinline__ short f2bf_fast(float x) {       // native cvt
    union { __hip_bfloat16 h; short s; } u;
    u.h = __float2bfloat16(x);
    return u.s;
}
__device__ __forceinline__ float bf2f(unsigned short s) {
    union { unsigned u; float f; } v; v.u = ((unsigned)s) << 16;
    return v.f;
}
// byte offset of bf16 element k in a 256B row with 16-slot XOR swizzle
__device__ __forceinline__ int swz(int row, int k) {
    return row * 256 + ((((k >> 3) ^ (row & 15)) << 4) | ((k & 7) << 1));
}

// ---------------- k1: per-node precompute, 4 rows/block (512 blocks, 2 blk/CU)
__global__ __launch_bounds__(128) void k1_pre(const float* __restrict__ nf,
                                              const float* __restrict__ We1,
                                              float* __restrict__ A_ws,
                                              float* __restrict__ Bm_ws) {
    const int b  = blockIdx.x >> 5;
    const int r0 = (blockIdx.x & 31) << 2;
    const int h  = threadIdx.x;
    __shared__ float rows[4][128];
#pragma unroll
    for (int r = 0; r < 4; ++r)
        rows[r][h] = nf[((size_t)(b * N_ + r0 + r)) * NF_ + h];
    __syncthreads();
    float a[4], bm[4];
#pragma unroll
    for (int r = 0; r < 4; ++r) { a[r] = 0.f; bm[r] = 0.f; }
    for (int c = 0; c < NF_; ++c) {
        const float w1 = We1[c * H_ + h];
        const float w2 = We1[(NF_ + c) * H_ + h];
#pragma unroll
        for (int r = 0; r < 4; ++r) {
            const float x = rows[r][c];
            a[r]  = fmaf(x, w1, a[r]);
            bm[r] = fmaf(x, w2, bm[r]);
        }
    }
#pragma unroll
    for (int r = 0; r < 4; ++r) {
        A_ws [((size_t)(b * N_ + r0 + r)) * H_ + h] = a[r];
        Bm_ws[((size_t)(b * N_ + r0 + r)) * H_ + h] = bm[r];
    }
}

// ---------------- k2: wave-per-row, swizzled LDS, 2-chunk register blocking ----
// LDS layout (bytes); total 143104 < 160 KiB
#define OFF_BM    0         // 32768: Bm bf16 [128] rows x 256 B, swizzled
#define OFF_W2T   32768     // 32768: We2^T bf16, swizzled
#define OFF_WC1X  65536     // 36864: [Wc1^T | Wi | 0] bf16 144 rows, swizzled
#define OFF_MB    102400    // 32768: 8 per-wave 16x256B transpose slabs, swizzled
#define OFF_AW    135168    // 4096: 8 A-rows f32
#define OFF_WAB   139264    // 1024: We1 rows 256/257 f32
#define OFF_WC2   140288    // 512
#define OFF_POSJ  140800    // 1536
#define OFF_VALJ  142336    // 512
#define OFF_POSI  142848    // 96 (pad 128)
#define OFF_VALI  142976    // 32 (pad 64)
#define OFF_CINV  143040    // 64 (one f32, padded)
#define SMEM_K2   143104

__global__ __launch_bounds__(512, 2) void k2_edge(
        const float* __restrict__ pos,
        const float* __restrict__ valid,
        const float* __restrict__ adj,
        const float* __restrict__ We1,
        const float* __restrict__ We2,
        const float* __restrict__ Wc1,
        const float* __restrict__ Wc2,
        const float* __restrict__ Wi,
        const float* __restrict__ A_ws,
        const float* __restrict__ Bm_ws,
        float* __restrict__ msg_ws,
        float* __restrict__ pos_out) {
    __shared__ __align__(16) char smem[SMEM_K2];
    char* BMb   = smem + OFF_BM;
    char* W2Tb  = smem + OFF_W2T;
    char* WC1Xb = smem + OFF_WC1X;
    char* MBb   = smem + OFF_MB;
    float* AWf  = (float*)(smem + OFF_AW);
    float* WABf = (float*)(smem + OFF_WAB);
    float* wc2s = (float*)(smem + OFF_WC2);
    float* posj = (float*)(smem + OFF_POSJ);
    float* valj = (float*)(smem + OFF_VALJ);
    float* posi = (float*)(smem + OFF_POSI);
    float* vali = (float*)(smem + OFF_VALI);
    float* cinv_s = (float*)(smem + OFF_CINV);

    const int tid = threadIdx.x;
    const int b   = blockIdx.x >> 4;
    const int i0  = (blockIdx.x & 15) << 3;

    // ---- staging ----
    for (int q = tid; q < (N_ * H_) / 4; q += 512) {       // Bm -> bf16, swizzled
        const int j  = q >> 5;
        const int ch = (q << 2) & 127;
        const float4 v = *(const float4*)(Bm_ws + ((size_t)(b * N_ + j)) * H_ + ch);
        ushort4 o;
        o.x = f2bf(v.x); o.y = f2bf(v.y); o.z = f2bf(v.z); o.w = f2bf(v.w);
        *(ushort4*)(BMb + swz(j, ch)) = o;
    }
    for (int x = tid; x < H_ * H_; x += 512) {             // We2^T, swizzled
        const int k = x >> 7, n = x & 127;
        *(unsigned short*)(W2Tb + swz(n, k)) = f2bf(We2[x]);
    }
    for (int x = tid; x < H_ * H_; x += 512) {             // Wc1^T, swizzled
        const int k = x >> 7, n = x & 127;
        *(unsigned short*)(WC1Xb + swz(n, k)) = f2bf(Wc1[x]);
    }
    if (tid < 128)                                          // Wi -> row 128 (key 0)
        *(unsigned short*)(WC1Xb + swz(128, tid)) = f2bf(Wi[tid]);
    for (int x = tid; x < 15 * 128; x += 512)               // zero rows 129..143
        ((unsigned short*)(WC1Xb + 129 * 256))[x] = 0;
    for (int x = tid; x < 8 * H_; x += 512)                 // A rows f32
        AWf[x] = A_ws[((size_t)(b * N_ + i0)) * H_ + x];
    if (tid < 256) WABf[tid] = We1[256 * H_ + tid];         // rows 256/257 f32
    if (tid < 128) {
        wc2s[tid] = Wc2[tid];
        valj[tid] = valid[b * N_ + tid];
    }
    if (tid >= 128) posj[tid - 128] = pos[b * N_ * 3 + (tid - 128)];   // 384 floats
    if (tid < 24)   posi[tid] = pos[b * N_ * 3 + i0 * 3 + tid];
    if (tid >= 32 && tid < 40) vali[tid - 32] = valid[b * N_ + i0 + (tid - 32)];
    if (tid >= 448) {                                        // fold kC: Cinv in wave 7
        const int t = tid - 448;
        float v = valid[b * N_ + t] + valid[b * N_ + 64 + t];
#pragma unroll
        for (int m = 32; m >= 1; m >>= 1) v += __shfl_down(v, m, 64);
        if (t == 0) cinv_s[0] = 1.0f / (v - 1.0f);
    }
    __syncthreads();

    const int w  = tid >> 6;
    const int l  = tid & 63;
    const int lr = l & 15;
    const int lg = l >> 4;
    const int i  = i0 + w;
    char* MBw = MBb + w * 4096;                 // per-wave 16x256B slab

    int csx[4];                                  // swizzled slot offset per ks
#pragma unroll
    for (int ks = 0; ks < 4; ++ks) csx[ks] = ((ks * 4 + lg) ^ lr) << 4;

    float wc2v[8];
#pragma unroll
    for (int nt = 0; nt < 8; ++nt) wc2v[nt] = wc2s[nt * 16 + lr];
    const float vi   = vali[w];
    const float pix  = posi[w * 3 + 0], piy = posi[w * 3 + 1], piz = posi[w * 3 + 2];
    const float cinv = cinv_s[0];

    float msg[8] = {0.f, 0.f, 0.f, 0.f, 0.f, 0.f, 0.f, 0.f};
    float px = 0.f, py = 0.f, pz = 0.f;
    const floatx4 zf = {0.f, 0.f, 0.f, 0.f};

    for (int jp = 0; jp < 4; ++jp) {            // 2 chunks of 16 edges per pass
        const int j0 = jp * 32;
        float adjv[2], vmv[2], dst[2], vnx[2], vny[2], vnz[2];
#pragma unroll
        for (int c = 0; c < 2; ++c) {
            const int jj = j0 + c * 16 + lr;    // jj & 15 == lr -> swizzle key = lr
            adjv[c] = adj[((size_t)(b * N_ + i)) * N_ + jj];
            const float vj = valj[jj];
            const float vx = pix - posj[jj * 3 + 0];
            const float vy = piy - posj[jj * 3 + 1];
            const float vz = piz - posj[jj * 3 + 2];
            dst[c] = vx * vx + vy * vy + vz * vz;
            vmv[c] = vi * vj;
            const float rn = __builtin_amdgcn_rcpf(fmaxf(sqrtf(dst[c]), 1e-10f));
            vnx[c] = vx * rn; vny[c] = vy * rn; vnz[c] = vz * rn;
        }

        // ---- preact build + silu -> A-fragments, both chunks ----
        short8 af[2][4];
#pragma unroll
        for (int c = 0; c < 2; ++c) {
            const int jj = j0 + c * 16 + lr;
#pragma unroll
            for (int ks = 0; ks < 4; ++ks) {
                const int co = ks * 32 + lg * 8;
                const short8 bm8 = *(const short8*)(BMb + jj * 256 + csx[ks]);
                const floatx4 a0 = *(const floatx4*)(AWf + w * 128 + co);
                const floatx4 a1 = *(const floatx4*)(AWf + w * 128 + co + 4);
                const floatx4 wa0 = *(const floatx4*)(WABf + co);
                const floatx4 wa1 = *(const floatx4*)(WABf + co + 4);
                const floatx4 wb0 = *(const floatx4*)(WABf + 128 + co);
                const floatx4 wb1 = *(const floatx4*)(WABf + 128 + co + 4);
#pragma unroll
                for (int e = 0; e < 8; ++e) {
                    const float aw = (e < 4) ? a0[e & 3] : a1[e & 3];
                    const float wa = (e < 4) ? wa0[e & 3] : wa1[e & 3];
                    const float wb = (e < 4) ? wb0[e & 3] : wb1[e & 3];
                    const float pre = aw + bf2f((unsigned short)bm8[e])
                                    + dst[c] * wa + adjv[c] * wb;
                    af[c][ks][e] = f2bf_fast(silu_f(pre));
                }
            }
        }

        // ---- GEMM1: shared weight fragments, 2 chunks per load ----
        floatx4 acc1[2][8];
#pragma unroll
        for (int c = 0; c < 2; ++c)
#pragma unroll
            for (int nt = 0; nt < 8; ++nt) acc1[c][nt] = zf;
#pragma unroll
        for (int nt = 0; nt < 8; ++nt)
#pragma unroll
            for (int ks = 0; ks < 4; ++ks) {
                const short8 bf = *(const short8*)(W2Tb + (nt * 16 + lr) * 256 + csx[ks]);
                acc1[0][nt] = __builtin_amdgcn_mfma_f32_16x16x32_bf16(af[0][ks], bf, acc1[0][nt], 0, 0, 0);
                acc1[1][nt] = __builtin_amdgcn_mfma_f32_16x16x32_bf16(af[1][ks], bf, acc1[1][nt], 0, 0, 0);
            }
        // m = silu(.) : lane holds edge lg*4+r, channel nt*16+lr
#pragma unroll
        for (int c = 0; c < 2; ++c)
#pragma unroll
            for (int nt = 0; nt < 8; ++nt)
#pragma unroll
                for (int r = 0; r < 4; ++r)
                    acc1[c][nt][r] = silu_f(acc1[c][nt][r]);

        // ---- re-fragment m via swizzled per-wave slab (same-wave ordering) ----
        short8 af2[2][4];
#pragma unroll
        for (int c = 0; c < 2; ++c) {
#pragma unroll
            for (int nt = 0; nt < 8; ++nt)
#pragma unroll
                for (int r = 0; r < 4; ++r)
                    *(unsigned short*)(MBw + swz(lg * 4 + r, nt * 16 + lr)) =
                        (unsigned short)f2bf_fast(acc1[c][nt][r]);
#pragma unroll
            for (int ks = 0; ks < 4; ++ks)
                af2[c][ks] = *(const short8*)(MBw + lr * 256 + csx[ks]);
        }

        // ---- gate tiles: shared weight fragments ----
        floatx4 accg[2];
        accg[0] = zf; accg[1] = zf;
#pragma unroll
        for (int ks = 0; ks < 4; ++ks) {
            const short8 bf = *(const short8*)(WC1Xb + (128 + lr) * 256 + csx[ks]);
            accg[0] = __builtin_amdgcn_mfma_f32_16x16x32_bf16(af2[0][ks], bf, accg[0], 0, 0, 0);
            accg[1] = __builtin_amdgcn_mfma_f32_16x16x32_bf16(af2[1][ks], bf, accg[1], 0, 0, 0);
        }
#pragma unroll
        for (int c = 0; c < 2; ++c) {
            float t4[4];
#pragma unroll
            for (int r = 0; r < 4; ++r) {
                const float ep  = __shfl(accg[c][r], l & 48);
                const float ajr = __shfl(adjv[c], (l & 48) | (lg * 4 + r));
                t4[r] = sigm_f(ep) * ajr;
            }
#pragma unroll
            for (int nt = 0; nt < 8; ++nt)
                msg[nt] += acc1[c][nt][0] * t4[0] + acc1[c][nt][1] * t4[1]
                         + acc1[c][nt][2] * t4[2] + acc1[c][nt][3] * t4[3];
        }

        // ---- GEMM2 phi tiles streamed; shared weight fragments ----
        float ph[2][4] = {{0.f, 0.f, 0.f, 0.f}, {0.f, 0.f, 0.f, 0.f}};
#pragma unroll
        for (int nt = 0; nt < 8; ++nt) {
            floatx4 acc2a = zf, acc2b = zf;
#pragma unroll
            for (int ks = 0; ks < 4; ++ks) {
                const short8 bf = *(const short8*)(WC1Xb + (nt * 16 + lr) * 256 + csx[ks]);
                acc2a = __builtin_amdgcn_mfma_f32_16x16x32_bf16(af2[0][ks], bf, acc2a, 0, 0, 0);
                acc2b = __builtin_amdgcn_mfma_f32_16x16x32_bf16(af2[1][ks], bf, acc2b, 0, 0, 0);
            }
            const float wv = wc2v[nt];
#pragma unroll
            for (int r = 0; r < 4; ++r) {
                ph[0][r] = fmaf(silu_f(acc2a[r]), wv, ph[0][r]);
                ph[1][r] = fmaf(silu_f(acc2b[r]), wv, ph[1][r]);
            }
        }
#pragma unroll
        for (int msk = 1; msk <= 8; msk <<= 1)
#pragma unroll
            for (int c = 0; c < 2; ++c)
#pragma unroll
                for (int r = 0; r < 4; ++r)
                    ph[c][r] += __shfl_xor(ph[c][r], msk);
        // gather phi for this lane's own edge, both chunks
        const int src = ((lr >> 2) << 4) | lr;
        const int rr  = lr & 3;
#pragma unroll
        for (int c = 0; c < 2; ++c) {
            const float q0 = __shfl(ph[c][0], src), q1 = __shfl(ph[c][1], src);
            const float q2 = __shfl(ph[c][2], src), q3 = __shfl(ph[c][3], src);
            const float phl = rr == 0 ? q0 : rr == 1 ? q1 : rr == 2 ? q2 : q3;
            const float pm = phl * vmv[c];
            px = fmaf(vnx[c], pm, px); py = fmaf(vny[c], pm, py); pz = fmaf(vnz[c], pm, pz);
        }
    }

    // ---- epilogue (register reductions, no LDS) ----
#pragma unroll
    for (int msk = 16; msk <= 32; msk <<= 1)
#pragma unroll
        for (int nt = 0; nt < 8; ++nt)
            msg[nt] += __shfl_xor(msg[nt], msk);
    if (l < 16) {
#pragma unroll
        for (int nt = 0; nt < 8; ++nt)
            msg_ws[((size_t)(b * N_ + i)) * H_ + nt * 16 + l] = msg[nt];
    }
#pragma unroll
    for (int msk = 1; msk <= 8; msk <<= 1) {
        px += __shfl_xor(px, msk);
        py += __shfl_xor(py, msk);
        pz += __shfl_xor(pz, msk);
    }
    if (l == 0) {
        const size_t o = ((size_t)(b * N_ + i)) * 3;
        pos_out[o + 0] = pos[o + 0] + cinv * px;
        pos_out[o + 1] = pos[o + 1] + cinv * py;
        pos_out[o + 2] = pos[o + 2] + cinv * pz;
    }
}

// ---------------- k3: node MLP, 4 rows/block (512 blocks, 2 blk/CU) ----------
__global__ __launch_bounds__(128) void k3_node(
        const float* __restrict__ nf,
        const float* __restrict__ Wn1,
        const float* __restrict__ Wn2,
        const float* __restrict__ msg_ws,
        float* __restrict__ out) {
    const int b  = blockIdx.x >> 5;
    const int r0 = (blockIdx.x & 31) << 2;
    const int h  = threadIdx.x;
    __shared__ float in_s[4][256];
    __shared__ float t_s[4][128];
#pragma unroll
    for (int r = 0; r < 4; ++r) {
        in_s[r][h]       = nf[((size_t)(b * N_ + r0 + r)) * NF_ + h];
        in_s[r][128 + h] = msg_ws[((size_t)(b * N_ + r0 + r)) * H_ + h];
    }
    __syncthreads();
    float acc[4];
#pragma unroll
    for (int r = 0; r < 4; ++r) acc[r] = 0.f;
    for (int c = 0; c < 256; ++c) {
        const float wv = Wn1[c * H_ + h];
#pragma unroll
        for (int r = 0; r < 4; ++r) acc[r] = fmaf(in_s[r][c], wv, acc[r]);
    }
#pragma unroll
    for (int r = 0; r < 4; ++r) t_s[r][h] = silu_f(acc[r]);
    __syncthreads();
    float o[4];
#pragma unroll
    for (int r = 0; r < 4; ++r) o[r] = 0.f;
    for (int c = 0; c < 128; ++c) {
        const float wv = Wn2[c * NF_ + h];
#pragma unroll
        for (int r = 0; r < 4; ++r) o[r] = fmaf(t_s[r][c], wv, o[r]);
    }
#pragma unroll
    for (int r = 0; r < 4; ++r)
        out[((size_t)(b * N_ + r0 + r)) * NF_ + h] = in_s[r][h] + o[r];
}

extern "C" void kernel_launch(void* const* d_in, const int* in_sizes, int n_in,
                              void* d_out, int out_size, void* d_ws, size_t ws_size,
                              hipStream_t stream) {
    const float* node_feat = (const float*)d_in[0];
    const float* pos   = (const float*)d_in[1];
    const float* valid = (const float*)d_in[2];
    const float* adj   = (const float*)d_in[3];
    const float* We1   = (const float*)d_in[4];
    const float* We2   = (const float*)d_in[5];
    const float* Wc1   = (const float*)d_in[6];
    const float* Wc2   = (const float*)d_in[7];
    const float* Wn1   = (const float*)d_in[8];
    const float* Wn2   = (const float*)d_in[9];
    const float* Wi    = (const float*)d_in[10];

    float* out     = (float*)d_out;
    float* pos_out = out + (size_t)B_ * N_ * NF_;

    const size_t node_elems = (size_t)B_ * N_ * H_;
    if (ws_size < 3 * node_elems * sizeof(float)) return;
    float* A_ws   = (float*)d_ws;
    float* Bm_ws  = A_ws + node_elems;
    float* msg_ws = Bm_ws + node_elems;

    k1_pre<<<B_ * 32, 128, 0, stream>>>(node_feat, We1, A_ws, Bm_ws);
    k2_edge<<<B_ * 16, 512, 0, stream>>>(pos, valid, adj, We1, We2, Wc1, Wc2, Wi,
                                         A_ws, Bm_ws, msg_ws, pos_out);
    k3_node<<<B_ * 32, 128, 0, stream>>>(node_feat, Wn1, Wn2, msg_ws, out);
}